// Round 8
// baseline (262.809 us; speedup 1.0000x reference)
//
#include <hip/hip_runtime.h>
#include <cstdint>

typedef unsigned short u16;
typedef __bf16 bf16x8 __attribute__((ext_vector_type(8)));
typedef float f32x4 __attribute__((ext_vector_type(4)));
typedef float f32x16 __attribute__((ext_vector_type(16)));
typedef uint32_t u32x4 __attribute__((ext_vector_type(4)));

#define SCALE_LOG2E (0.125f * 1.44269504088896340736f)

__device__ __forceinline__ u16 f2bf(float f) {
    uint32_t u = __builtin_bit_cast(uint32_t, f);
    u += 0x7fff + ((u >> 16) & 1);
    return (u16)(u >> 16);
}
__device__ __forceinline__ float bf2f(u16 u) {
    return __builtin_bit_cast(float, (uint32_t)u << 16);
}

__device__ __forceinline__ void gload_lds16(const void* g, void* l) {
    __builtin_amdgcn_global_load_lds(
        (__attribute__((address_space(1))) void*)g,
        (__attribute__((address_space(3))) void*)l, 16, 0, 0);
}

// ---------------- fused f32 -> bf16 convert for all 7 tensors ----------------
__global__ __launch_bounds__(256) void cvt_all(const float* __restrict__ s0,
                                               const float* __restrict__ s1,
                                               const float* __restrict__ s2,
                                               const float* __restrict__ s3,
                                               const float* __restrict__ s4,
                                               const float* __restrict__ s5,
                                               const float* __restrict__ s6,
                                               u16* __restrict__ d0, u16* __restrict__ d1,
                                               u16* __restrict__ d2, u16* __restrict__ d3,
                                               u16* __restrict__ d4) {
    int i = blockIdx.x * 256 + threadIdx.x;
    const float* src;
    u16* dst;
    int off;
    if (i < 524288)       { src = s0; dst = d0; off = i; }
    else if (i < 1572864) { src = s1; dst = d1; off = i - 524288; }
    else if (i < 1835008) { src = s2; dst = d2; off = i - 1572864; }
    else if (i < 2097152) { src = s3; dst = d2 + (size_t)1024 * 1024; off = i - 1835008; }
    else if (i < 2621440) { src = s4; dst = d3; off = i - 2097152; }
    else if (i < 2883584) { src = s5; dst = d3 + (size_t)2048 * 1024; off = i - 2621440; }
    else                  { src = s6; dst = d4; off = i - 2883584; }
    float4 v = ((const float4*)src)[off];
    ushort4 o;
    o.x = f2bf(v.x); o.y = f2bf(v.y); o.z = f2bf(v.z); o.w = f2bf(v.w);
    ((ushort4*)dst)[off] = o;
}

// ---------------- merged swapped-operand Q12 + KV GEMM, 1024 blocks ----------
__global__ __launch_bounds__(256) void gemm_qkv(const u16* __restrict__ Wq,
                                                const u16* __restrict__ Xq,
                                                const u16* __restrict__ Wkv,
                                                const u16* __restrict__ Xk,
                                                u16* __restrict__ q1s, u16* __restrict__ q2s,
                                                u16* __restrict__ k1f, u16* __restrict__ v1f,
                                                u16* __restrict__ k2f) {
    __shared__ u16 As[2][128 * 32];
    __shared__ u16 Bs[2][128 * 32];
    const int K = 1024;
    const int bid = blockIdx.x;
    int mode, bm, bn;
    const u16 *A, *B;
    if (bid < 256) {
        mode = 0; bm = bid >> 4; bn = bid & 15; A = Wq; B = Xq;
    } else {
        int t = bid - 256;
        mode = 1; bm = t % 24; bn = t / 24; A = Wkv; B = Xk;
    }
    const int tid = threadIdx.x;
    const int l = tid & 63, w = tid >> 6;
    const int c = l & 15, g = l >> 4;
    const int wr = w >> 1, wc = w & 1;

    f32x4 acc[4][4];
#pragma unroll
    for (int i = 0; i < 4; i++)
#pragma unroll
        for (int j = 0; j < 4; j++) acc[i][j] = f32x4{0.f, 0.f, 0.f, 0.f};

    const u16* Abase = A + (size_t)(bm * 128) * K;
    const u16* Bbase = B + (size_t)(bn * 128) * K;
    const int r0 = 32 * w + (l >> 2);
    const int chsw = ((l & 3) ^ ((l >> 3) & 3)) * 8;
    const int gsw = 8 * (g ^ ((c >> 1) & 3));

    int cur = 0;
    gload_lds16(Abase + (size_t)r0 * K + chsw,        &As[0][32 * w * 32]);
    gload_lds16(Abase + (size_t)(r0 + 16) * K + chsw, &As[0][(32 * w + 16) * 32]);
    gload_lds16(Bbase + (size_t)r0 * K + chsw,        &Bs[0][32 * w * 32]);
    gload_lds16(Bbase + (size_t)(r0 + 16) * K + chsw, &Bs[0][(32 * w + 16) * 32]);
    __syncthreads();

    for (int t = 0; t < 32; ++t) {
        if (t < 31) {
            const int kb = (t + 1) * 32;
            gload_lds16(Abase + (size_t)r0 * K + kb + chsw,        &As[cur ^ 1][32 * w * 32]);
            gload_lds16(Abase + (size_t)(r0 + 16) * K + kb + chsw, &As[cur ^ 1][(32 * w + 16) * 32]);
            gload_lds16(Bbase + (size_t)r0 * K + kb + chsw,        &Bs[cur ^ 1][32 * w * 32]);
            gload_lds16(Bbase + (size_t)(r0 + 16) * K + kb + chsw, &Bs[cur ^ 1][(32 * w + 16) * 32]);
        }
        bf16x8 af[4], bfr[4];
#pragma unroll
        for (int mi = 0; mi < 4; mi++)
            af[mi] = *(const bf16x8*)&As[cur][(64 * wr + 16 * mi + c) * 32 + gsw];
#pragma unroll
        for (int ni = 0; ni < 4; ni++)
            bfr[ni] = *(const bf16x8*)&Bs[cur][(64 * wc + 16 * ni + c) * 32 + gsw];
#pragma unroll
        for (int mi = 0; mi < 4; mi++)
#pragma unroll
            for (int ni = 0; ni < 4; ni++)
                acc[mi][ni] = __builtin_amdgcn_mfma_f32_16x16x32_bf16(
                    af[mi], bfr[ni], acc[mi][ni], 0, 0, 0);
        __syncthreads();
        cur ^= 1;
    }

#pragma unroll
    for (int mi = 0; mi < 4; mi++) {
        const int m0 = bm * 128 + 64 * wr + 16 * mi + 4 * g;
#pragma unroll
        for (int ni = 0; ni < 4; ni++) {
            const int n = bn * 128 + 64 * wc + 16 * ni + c;
            f32x4 v = acc[mi][ni];
            if (mode == 0) {
                int half = m0 >> 10, feat = m0 & 1023;
                int h = feat >> 6, hd0 = feat & 63;
                int b = n >> 10, nq = n & 1023;
                int bh = b * 16 + h;
                u16* dst = half ? q2s : q1s;
                size_t idx = ((size_t)(bh * 32 + (nq >> 5)) * 4 + (hd0 >> 4)) * 512
                           + (((hd0 >> 3) & 1) * 32 + (nq & 31)) * 8 + (hd0 & 7);
                ushort4 o;
                o.x = f2bf(v[0] * SCALE_LOG2E); o.y = f2bf(v[1] * SCALE_LOG2E);
                o.z = f2bf(v[2] * SCALE_LOG2E); o.w = f2bf(v[3] * SCALE_LOG2E);
                *(ushort4*)(dst + idx) = o;
            } else {
                int b = n >> 11, nk = n & 2047;
                if (m0 < 1024) {
                    int h = m0 >> 6, hd0 = m0 & 63, bh = b * 16 + h;
                    size_t idx = ((size_t)(bh * 64 + (nk >> 5)) * 4 + (hd0 >> 4)) * 512
                               + (((hd0 >> 3) & 1) * 32 + (nk & 31)) * 8 + (hd0 & 7);
                    ushort4 o;
                    o.x = f2bf(v[0]); o.y = f2bf(v[1]); o.z = f2bf(v[2]); o.w = f2bf(v[3]);
                    *(ushort4*)(k1f + idx) = o;
                } else if (m0 < 2048) {
                    int feat = m0 - 1024, h = feat >> 6, hd0 = feat & 63, bh = b * 16 + h;
#pragma unroll
                    for (int j = 0; j < 4; j++) {
                        int hd = hd0 + j;
                        size_t idx = ((size_t)(bh * 128 + (nk >> 4)) * 2 + (hd >> 5)) * 512
                                   + (((nk >> 3) & 1) * 32 + (hd & 31)) * 8 + (nk & 7);
                        v1f[idx] = f2bf(v[j]);
                    }
                } else {
                    int feat = m0 - 2048, h = feat >> 6, hd0 = feat & 63, bh = b * 16 + h;
                    size_t idx = ((size_t)(bh * 64 + (nk >> 5)) * 4 + (hd0 >> 4)) * 512
                               + (((hd0 >> 3) & 1) * 32 + (nk & 31)) * 8 + (hd0 & 7);
                    ushort4 o;
                    o.x = f2bf(v[0]); o.y = f2bf(v[1]); o.z = f2bf(v[2]); o.w = f2bf(v[3]);
                    *(ushort4*)(k2f + idx) = o;
                }
            }
        }
    }
}

// ---------------- proj GEMM, tile 128x64, dbuf + swizzle -> 256 blocks -------
__global__ __launch_bounds__(256) void gemm_proj(const u16* __restrict__ A,
                                                 const u16* __restrict__ B,
                                                 float* __restrict__ fo,
                                                 const float* __restrict__ bias) {
    __shared__ u16 As[2][128 * 32];
    __shared__ u16 Bs[2][64 * 32];
    const int K = 1024;
    const int bm = blockIdx.x >> 4, bn = blockIdx.x & 15;
    const int tid = threadIdx.x;
    const int l = tid & 63, w = tid >> 6;
    const int c = l & 15, g = l >> 4;
    const int wr = w >> 1, wc = w & 1;

    f32x4 acc[4][2];
#pragma unroll
    for (int i = 0; i < 4; i++)
#pragma unroll
        for (int j = 0; j < 2; j++) acc[i][j] = f32x4{0.f, 0.f, 0.f, 0.f};

    const u16* Abase = A + (size_t)(bm * 128) * K;
    const u16* Bbase = B + (size_t)(bn * 64) * K;
    const int rA = 32 * w + (l >> 2);
    const int rB = 16 * w + (l >> 2);
    const int chsw = ((l & 3) ^ ((l >> 3) & 3)) * 8;
    const int gsw = 8 * (g ^ ((c >> 1) & 3));

    int cur = 0;
    gload_lds16(Abase + (size_t)rA * K + chsw,        &As[0][32 * w * 32]);
    gload_lds16(Abase + (size_t)(rA + 16) * K + chsw, &As[0][(32 * w + 16) * 32]);
    gload_lds16(Bbase + (size_t)rB * K + chsw,        &Bs[0][16 * w * 32]);
    __syncthreads();

    for (int t = 0; t < 32; ++t) {
        if (t < 31) {
            const int kb = (t + 1) * 32;
            gload_lds16(Abase + (size_t)rA * K + kb + chsw,        &As[cur ^ 1][32 * w * 32]);
            gload_lds16(Abase + (size_t)(rA + 16) * K + kb + chsw, &As[cur ^ 1][(32 * w + 16) * 32]);
            gload_lds16(Bbase + (size_t)rB * K + kb + chsw,        &Bs[cur ^ 1][16 * w * 32]);
        }
        bf16x8 af[4], bfr[2];
#pragma unroll
        for (int mi = 0; mi < 4; mi++)
            af[mi] = *(const bf16x8*)&As[cur][(64 * wr + 16 * mi + c) * 32 + gsw];
#pragma unroll
        for (int ni = 0; ni < 2; ni++)
            bfr[ni] = *(const bf16x8*)&Bs[cur][(32 * wc + 16 * ni + c) * 32 + gsw];
#pragma unroll
        for (int mi = 0; mi < 4; mi++)
#pragma unroll
            for (int ni = 0; ni < 2; ni++)
                acc[mi][ni] = __builtin_amdgcn_mfma_f32_16x16x32_bf16(
                    af[mi], bfr[ni], acc[mi][ni], 0, 0, 0);
        __syncthreads();
        cur ^= 1;
    }

#pragma unroll
    for (int mi = 0; mi < 4; mi++)
#pragma unroll
        for (int ni = 0; ni < 2; ni++)
#pragma unroll
            for (int j = 0; j < 4; j++) {
                int m = bm * 128 + 64 * wr + 16 * mi + 4 * g + j;
                int n = bn * 64 + 32 * wc + 16 * ni + c;
                fo[(size_t)m * 1024 + n] = acc[mi][ni][j] + bias[n];
            }
}

// ---------------- dual flash attention, swapped-QK 32x32, LDS-staged K/V -----
// 4 waves/block share (bh, s): K1/K2/V tiles staged ONCE into LDS (12 x 1KB
// chunks, 3 per wave, global_load_lds), double-buffered 2-phase pipeline.
// Cuts L2 read traffic 4x and hides staging latency under compute.
__global__ __launch_bounds__(256) void attn_kernel(const u16* __restrict__ q1s,
                                                   const u16* __restrict__ q2s,
                                                   const u16* __restrict__ k1fm,
                                                   const u16* __restrict__ k2fm,
                                                   const u16* __restrict__ v1fm,
                                                   u16* __restrict__ Opart,
                                                   float* __restrict__ Lpart) {
    __shared__ u16 kv[2][6144];   // [buf][K1 2048 | K2 2048 | V 2048] u16 = 12KB/buf
    const int tid = threadIdx.x;
    const int l = tid & 63, w = tid >> 6;
    const int c5 = l & 31, hf = l >> 5;
    const int bid = blockIdx.x;
    const int xcd = bid & 7, slot = bid >> 3;
    const int bh = xcd * 4 + (slot >> 5);
    const int r = slot & 31;
    const int qt = r >> 2, s = r & 3;
    const int b = bh >> 4, head = bh & 15;
    const int q0 = qt * 128 + w * 32;

    const u16* k1t = k1fm + (size_t)bh * 64 * 2048;
    const u16* k2t = k2fm + (size_t)bh * 64 * 2048;
    const u16* vt  = v1fm + (size_t)bh * 128 * 1024;
    const u16* bases[3] = {k1t, k2t, vt};

    // stage tile t32 into buf: wave w loads chunks 3w..3w+2 (1KB each)
    auto stage = [&](int buf, int t32) {
#pragma unroll
        for (int j = 0; j < 3; j++) {
            int q = w * 3 + j;                 // 0..11
            const u16* src = bases[q >> 2] + (size_t)t32 * 2048 + (q & 3) * 512 + l * 8;
            gload_lds16(src, &kv[buf][q * 512]);
        }
    };

    // Q fragments (fragment-major): contiguous 1KB wave-loads
    bf16x8 qB1[4], qB2[4];
    {
        const u16* p1 = q1s + ((size_t)(bh * 32 + (q0 >> 5)) * 4) * 512 + l * 8;
        const u16* p2 = q2s + ((size_t)(bh * 32 + (q0 >> 5)) * 4) * 512 + l * 8;
#pragma unroll
        for (int d = 0; d < 4; d++) {
            qB1[d] = *(const bf16x8*)(p1 + d * 512);
            qB2[d] = *(const bf16x8*)(p2 + d * 512);
        }
    }

    f32x16 O1[2], O2[2];
#pragma unroll
    for (int dh = 0; dh < 2; dh++)
#pragma unroll
        for (int i = 0; i < 16; i++) { O1[dh][i] = 0.f; O2[dh][i] = 0.f; }
    float la1 = 0.f, la2 = 0.f;

    stage(0, s * 16);
    __syncthreads();
    int cur = 0;

    for (int it = 0; it < 16; it++) {
        if (it < 15) stage(cur ^ 1, s * 16 + it + 1);

        const u16* bufp = &kv[cur][0];
        // ---- attn1 ----
        {
            bf16x8 kA[4];
#pragma unroll
            for (int d = 0; d < 4; d++)
                kA[d] = *(const bf16x8*)(bufp + d * 512 + l * 8);
            f32x16 S;
#pragma unroll
            for (int i = 0; i < 16; i++) S[i] = 0.f;
#pragma unroll
            for (int d = 0; d < 4; d++)
                S = __builtin_amdgcn_mfma_f32_32x32x16_bf16(kA[d], qB1[d], S, 0, 0, 0);
            uint32_t dpk[8];
#pragma unroll
            for (int i = 0; i < 8; i++) {
                float pa = __builtin_exp2f(S[2 * i]);
                float pb = __builtin_exp2f(S[2 * i + 1]);
                la1 += pa + pb;
                asm("v_cvt_pk_bf16_f32 %0, %1, %2" : "=v"(dpk[i]) : "v"(pa), "v"(pb));
            }
            uint32_t a0 = dpk[0], b0 = dpk[2], a1 = dpk[1], b1 = dpk[3];
            asm("v_permlane32_swap_b32 %0, %1" : "+v"(a0), "+v"(b0));
            asm("v_permlane32_swap_b32 %0, %1" : "+v"(a1), "+v"(b1));
            u32x4 t0 = {a0, a1, b0, b1};
            bf16x8 pf0 = __builtin_bit_cast(bf16x8, t0);
            uint32_t a2 = dpk[4], b2 = dpk[6], a3 = dpk[5], b3 = dpk[7];
            asm("v_permlane32_swap_b32 %0, %1" : "+v"(a2), "+v"(b2));
            asm("v_permlane32_swap_b32 %0, %1" : "+v"(a3), "+v"(b3));
            u32x4 t1 = {a2, a3, b2, b3};
            bf16x8 pf1 = __builtin_bit_cast(bf16x8, t1);
#pragma unroll
            for (int dh = 0; dh < 2; dh++) {
                bf16x8 v0 = *(const bf16x8*)(bufp + 4096 + dh * 512 + l * 8);
                bf16x8 v1 = *(const bf16x8*)(bufp + 4096 + (2 + dh) * 512 + l * 8);
                O1[dh] = __builtin_amdgcn_mfma_f32_32x32x16_bf16(pf0, v0, O1[dh], 0, 0, 0);
                O1[dh] = __builtin_amdgcn_mfma_f32_32x32x16_bf16(pf1, v1, O1[dh], 0, 0, 0);
            }
        }
        // ---- attn2 ----
        {
            bf16x8 kA[4];
#pragma unroll
            for (int d = 0; d < 4; d++)
                kA[d] = *(const bf16x8*)(bufp + 2048 + d * 512 + l * 8);
            f32x16 S;
#pragma unroll
            for (int i = 0; i < 16; i++) S[i] = 0.f;
#pragma unroll
            for (int d = 0; d < 4; d++)
                S = __builtin_amdgcn_mfma_f32_32x32x16_bf16(kA[d], qB2[d], S, 0, 0, 0);
            uint32_t dpk[8];
#pragma unroll
            for (int i = 0; i < 8; i++) {
                float pa = __builtin_exp2f(S[2 * i]);
                float pb = __builtin_exp2f(S[2 * i + 1]);
                la2 += pa + pb;
                asm("v_cvt_pk_bf16_f32 %0, %1, %2" : "=v"(dpk[i]) : "v"(pa), "v"(pb));
            }
            uint32_t a0 = dpk[0], b0 = dpk[2], a1 = dpk[1], b1 = dpk[3];
            asm("v_permlane32_swap_b32 %0, %1" : "+v"(a0), "+v"(b0));
            asm("v_permlane32_swap_b32 %0, %1" : "+v"(a1), "+v"(b1));
            u32x4 t0 = {a0, a1, b0, b1};
            bf16x8 pf0 = __builtin_bit_cast(bf16x8, t0);
            uint32_t a2 = dpk[4], b2 = dpk[6], a3 = dpk[5], b3 = dpk[7];
            asm("v_permlane32_swap_b32 %0, %1" : "+v"(a2), "+v"(b2));
            asm("v_permlane32_swap_b32 %0, %1" : "+v"(a3), "+v"(b3));
            u32x4 t1 = {a2, a3, b2, b3};
            bf16x8 pf1 = __builtin_bit_cast(bf16x8, t1);
#pragma unroll
            for (int dh = 0; dh < 2; dh++) {
                bf16x8 v0 = *(const bf16x8*)(bufp + 4096 + dh * 512 + l * 8);
                bf16x8 v1 = *(const bf16x8*)(bufp + 4096 + (2 + dh) * 512 + l * 8);
                O2[dh] = __builtin_amdgcn_mfma_f32_32x32x16_bf16(pf0, v0, O2[dh], 0, 0, 0);
                O2[dh] = __builtin_amdgcn_mfma_f32_32x32x16_bf16(pf1, v1, O2[dh], 0, 0, 0);
            }
        }
        __syncthreads();
        cur ^= 1;
    }

    la1 += __shfl_xor(la1, 32, 64);
    la2 += __shfl_xor(la2, 32, 64);

    // partial planes: [8][2048][1024] bf16, plane = s*2 + attn
#pragma unroll
    for (int dh = 0; dh < 2; dh++)
#pragma unroll
        for (int rr = 0; rr < 16; rr++) {
            int qrow = (rr & 3) + 8 * (rr >> 2) + 4 * hf;
            size_t rowg = (size_t)b * 1024 + q0 + qrow;
            size_t col = head * 64 + dh * 32 + c5;
            Opart[((size_t)(s * 2 + 0) * 2048 + rowg) * 1024 + col] = f2bf(O1[dh][rr]);
            Opart[((size_t)(s * 2 + 1) * 2048 + rowg) * 1024 + col] = f2bf(O2[dh][rr]);
        }
    if (hf == 0) {
        size_t rowg = (size_t)b * 1024 + q0 + c5;
        Lpart[((size_t)(s * 2 + 0) * 2048 + rowg) * 16 + head] = la1;
        Lpart[((size_t)(s * 2 + 1) * 2048 + rowg) * 16 + head] = la2;
    }
}

// ---------------- combine 4 kv-splits + diff + RMSNorm -> bf16 ----------------
__global__ __launch_bounds__(256) void combine_rms(const u16* __restrict__ Opart,
                                                   const float* __restrict__ Lpart,
                                                   const float* __restrict__ lam1,
                                                   const float* __restrict__ lam2,
                                                   const float* __restrict__ nw,
                                                   u16* __restrict__ xn) {
    const int row = blockIdx.x, t = threadIdx.x;
    const int h = t >> 4;
    float a1[4] = {0.f, 0.f, 0.f, 0.f}, a2[4] = {0.f, 0.f, 0.f, 0.f};
    float li1 = 0.f, li2 = 0.f;
#pragma unroll
    for (int s = 0; s < 4; s++) {
        ushort4 u1 = ((const ushort4*)(Opart + ((size_t)(s * 2 + 0) * 2048 + row) * 1024))[t];
        ushort4 u2 = ((const ushort4*)(Opart + ((size_t)(s * 2 + 1) * 2048 + row) * 1024))[t];
        a1[0] += bf2f(u1.x); a1[1] += bf2f(u1.y); a1[2] += bf2f(u1.z); a1[3] += bf2f(u1.w);
        a2[0] += bf2f(u2.x); a2[1] += bf2f(u2.y); a2[2] += bf2f(u2.z); a2[3] += bf2f(u2.w);
        li1 += Lpart[((size_t)(s * 2 + 0) * 2048 + row) * 16 + h];
        li2 += Lpart[((size_t)(s * 2 + 1) * 2048 + row) * 16 + h];
    }
    float lam = lam1[h] - lam2[h] + 0.1f;
    float i1 = 1.0f / li1, i2 = lam / li2;
    float x0 = a1[0] * i1 - a2[0] * i2;
    float x1 = a1[1] * i1 - a2[1] * i2;
    float x2 = a1[2] * i1 - a2[2] * i2;
    float x3 = a1[3] * i1 - a2[3] * i2;
    float ss = x0 * x0 + x1 * x1 + x2 * x2 + x3 * x3;
#pragma unroll
    for (int off = 1; off < 64; off <<= 1) ss += __shfl_xor(ss, off, 64);
    __shared__ float ws4[4];
    if ((t & 63) == 0) ws4[t >> 6] = ss;
    __syncthreads();
    float tot = ws4[0] + ws4[1] + ws4[2] + ws4[3];
    float rs = rsqrtf(tot * (1.0f / 1024.0f) + 1e-6f);
    float4 wv = ((const float4*)nw)[t];
    ushort4 o;
    o.x = f2bf(x0 * rs * wv.x);
    o.y = f2bf(x1 * rs * wv.y);
    o.z = f2bf(x2 * rs * wv.z);
    o.w = f2bf(x3 * rs * wv.w);
    ((ushort4*)(xn + (size_t)row * 1024))[t] = o;
}

extern "C" void kernel_launch(void* const* d_in, const int* in_sizes, int n_in,
                              void* d_out, int out_size, void* d_ws, size_t ws_size,
                              hipStream_t stream) {
    const float* query  = (const float*)d_in[0];
    const float* key    = (const float*)d_in[1];
    const float* q1_w   = (const float*)d_in[5];
    const float* q2_w   = (const float*)d_in[6];
    const float* kv1_w  = (const float*)d_in[7];
    const float* kv2_w  = (const float*)d_in[8];
    const float* proj_w = (const float*)d_in[9];
    const float* proj_b = (const float*)d_in[10];
    const float* norm_w = (const float*)d_in[11];
    const float* lam1   = (const float*)d_in[12];
    const float* lam2   = (const float*)d_in[13];
    float* out = (float*)d_out;

    char* ws = (char*)d_ws;
    size_t off = 0;
    auto alloc = [&](size_t bytes) {
        void* p = ws + off;
        off += (bytes + 255) & ~(size_t)255;
        return p;
    };
    u16* Xq   = (u16*)alloc((size_t)2048 * 1024 * 2);
    u16* Xk   = (u16*)alloc((size_t)4096 * 1024 * 2);
    u16* Wq   = (u16*)alloc((size_t)2048 * 1024 * 2);
    u16* Wkv  = (u16*)alloc((size_t)3072 * 1024 * 2);
    u16* Wp   = (u16*)alloc((size_t)1024 * 1024 * 2);
    u16* q1sb = (u16*)alloc((size_t)32 * 1024 * 64 * 2);
    u16* q2sb = (u16*)alloc((size_t)32 * 1024 * 64 * 2);
    u16* k1fb = (u16*)alloc((size_t)32 * 2048 * 64 * 2);
    u16* k2fb = (u16*)alloc((size_t)32 * 2048 * 64 * 2);
    u16* v1fb = (u16*)alloc((size_t)32 * 64 * 2048 * 2);
    u16* Opart = (u16*)alloc((size_t)8 * 2048 * 1024 * 2);
    float* Lpart = (float*)alloc((size_t)8 * 2048 * 16 * 4);
    u16* xn   = (u16*)alloc((size_t)2048 * 1024 * 2);

    cvt_all<<<12288, 256, 0, stream>>>(query, key, q1_w, q2_w, kv1_w, kv2_w, proj_w,
                                       Xq, Xk, Wq, Wkv, Wp);

    gemm_qkv<<<1024, 256, 0, stream>>>(Wq, Xq, Wkv, Xk, q1sb, q2sb, k1fb, v1fb, k2fb);

    attn_kernel<<<1024, 256, 0, stream>>>(q1sb, q2sb, k1fb, k2fb, v1fb, Opart, Lpart);

    combine_rms<<<2048, 256, 0, stream>>>(Opart, Lpart, lam1, lam2, norm_w, xn);

    gemm_proj<<<256, 256, 0, stream>>>(xn, Wp, out, proj_b);
}